// Round 2
// baseline (208.673 us; speedup 1.0000x reference)
//
#include <hip/hip_runtime.h>
#include <hip/hip_bf16.h>

typedef __bf16 bf16_t;
typedef __bf16 bf16x8 __attribute__((ext_vector_type(8)));
typedef float  f32x4  __attribute__((ext_vector_type(4)));

#define D_DIM 1024
#define N_LAB 64
#define ST_TOK 16384
#define QT_TOK 16384
#define CHUNK 4096

// ---------------- Kernel 1: proto build (scan + stream, no atomics) ------
// grid = 256 blocks: blockIdx = label*4 + dq (dim quarter, 256 dims each).
// Each block: scan tag/msk in 4096-token chunks -> LDS match list (capacity
// guaranteed: list size <= chunk size), then stream matching rows with
// coalesced f32x4 loads, accumulate in registers per wave, combine via LDS.
// Emits bf16 proto slice + p2 partial directly (k_finalize folded in).
__global__ __launch_bounds__(256) void k_proto(
    const float* __restrict__ s_emb, const int* __restrict__ tag,
    const int* __restrict__ msk, bf16_t* __restrict__ protoB,
    float* __restrict__ p2part)
{
    __shared__ int   list[CHUNK];
    __shared__ int   cnt;
    __shared__ float comb[4][256];
    __shared__ float red[4];

    const int tid   = threadIdx.x;
    const int lane  = tid & 63;
    const int wave  = tid >> 6;
    const int label = blockIdx.x >> 2;
    const int dq    = blockIdx.x & 3;

    f32x4 acc = {0.f, 0.f, 0.f, 0.f};
    int total = 0;

    if (tid == 0) cnt = 0;
    __syncthreads();

    const float* base = s_emb + (size_t)dq * 256 + lane * 4;

    for (int c = 0; c < ST_TOK; c += CHUNK) {
        // ---- scan: collect matching token indices into LDS list ----
        for (int i = tid; i < CHUNK; i += 256) {
            const int t = c + i;
            if (msk[t] && tag[t] == label) {
                const int p = atomicAdd(&cnt, 1);
                list[p] = t;
            }
        }
        __syncthreads();
        const int n = cnt;
        total += n;

        // ---- stream: each wave takes every 4th match ----
        for (int i = wave; i < n; i += 4) {
            const int tok = list[i];
            f32x4 v = *(const f32x4*)(base + (size_t)tok * D_DIM);
            acc += v;
        }
        __syncthreads();
        if (tid == 0) cnt = 0;
        __syncthreads();
    }

    // ---- combine the 4 waves' partial sums ----
    *(f32x4*)&comb[wave][lane * 4] = acc;
    __syncthreads();
    float v = comb[0][tid] + comb[1][tid] + comb[2][tid] + comb[3][tid];
    const float inv = 1.f / fmaxf((float)total, 1.f);
    v *= inv;
    protoB[(size_t)label * D_DIM + dq * 256 + tid] = (bf16_t)v;

    // ---- p2 partial (sum of squares of this block's 256 dims) ----
    float ss = v * v;
    for (int off = 32; off; off >>= 1) ss += __shfl_down(ss, off);
    if (lane == 0) red[wave] = ss;
    __syncthreads();
    if (tid == 0) p2part[label * 4 + dq] = red[0] + red[1] + red[2] + red[3];
}

// ---------------- Kernel 2: logits via bf16 MFMA ------------------------
// 256 blocks x 256 threads (4 waves). Wave: 16 query rows x all 64 labels.
// A frag: A[m=lane&15][k=quad*8+j]; B frag: B[k][n=lane&15], k=quad*8+j
// (B[k][n] = proto[n][k]). C/D: col=lane&15, row=quad*4+reg.
__global__ __launch_bounds__(256) void k_logits(
    const float* __restrict__ q_emb, const int* __restrict__ q_mask,
    const bf16_t* __restrict__ protoB, const float* __restrict__ p2part,
    float* __restrict__ out)
{
    const int tid  = threadIdx.x;
    const int wave = tid >> 6;
    const int lane = tid & 63;
    const int r15  = lane & 15;
    const int quad = lane >> 4;
    const int m_base = blockIdx.x * 64 + wave * 16;

    const float*  aptr = q_emb  + (size_t)(m_base + r15) * D_DIM + quad * 8;
    const bf16_t* bptr = protoB + (size_t)r15 * D_DIM + quad * 8;

    f32x4 acc[4] = {};
    float q2p = 0.f;

#pragma unroll 2
    for (int kk = 0; kk < D_DIM; kk += 32) {
        f32x4 a0 = *(const f32x4*)(aptr + kk);
        f32x4 a1 = *(const f32x4*)(aptr + kk + 4);
        bf16x8 af;
        af[0] = (bf16_t)a0[0]; af[1] = (bf16_t)a0[1];
        af[2] = (bf16_t)a0[2]; af[3] = (bf16_t)a0[3];
        af[4] = (bf16_t)a1[0]; af[5] = (bf16_t)a1[1];
        af[6] = (bf16_t)a1[2]; af[7] = (bf16_t)a1[3];
        q2p += a0[0]*a0[0] + a0[1]*a0[1] + a0[2]*a0[2] + a0[3]*a0[3]
             + a1[0]*a1[0] + a1[1]*a1[1] + a1[2]*a1[2] + a1[3]*a1[3];
#pragma unroll
        for (int t = 0; t < 4; ++t) {
            bf16x8 bfr = *(const bf16x8*)(bptr + (size_t)t * 16 * D_DIM + kk);
            acc[t] = __builtin_amdgcn_mfma_f32_16x16x32_bf16(af, bfr, acc[t], 0, 0, 0);
        }
    }

    // q2p: partial q2 for row r15 over this quad's k-subset; reduce quads.
    q2p += __shfl_xor(q2p, 16);
    q2p += __shfl_xor(q2p, 32);
    // now lane l holds full q2 of row (l & 15)

    float p2v[4];
#pragma unroll
    for (int t = 0; t < 4; ++t) {
        f32x4 pp = *(const f32x4*)(p2part + (size_t)(t * 16 + r15) * 4);
        p2v[t] = pp[0] + pp[1] + pp[2] + pp[3];
    }

#pragma unroll
    for (int r = 0; r < 4; ++r) {
        const int mrow = quad * 4 + r;
        const float q2 = __shfl(q2p, mrow);     // lane mrow holds q2[row=mrow]
        const int gm = m_base + mrow;
        const float qm = (float)q_mask[gm];
#pragma unroll
        for (int t = 0; t < 4; ++t) {
            const float val = -(q2 + p2v[t] - 2.f * acc[t][r]) * qm;
            out[(size_t)gm * N_LAB + t * 16 + r15] = val;
        }
    }
}

extern "C" void kernel_launch(void* const* d_in, const int* in_sizes, int n_in,
                              void* d_out, int out_size, void* d_ws, size_t ws_size,
                              hipStream_t stream) {
    const float* s_emb = (const float*)d_in[0];
    const int*   s_tag = (const int*)d_in[1];
    const int*   s_msk = (const int*)d_in[2];
    const float* q_emb = (const float*)d_in[3];
    const int*   q_msk = (const int*)d_in[4];
    (void)in_sizes; (void)n_in; (void)out_size; (void)ws_size;

    char* ws = (char*)d_ws;
    bf16_t* protoB = (bf16_t*)ws;                 // 64*1024*2 = 131072 B
    float*  p2part = (float*)(ws + 131072);       // 64*4*4    = 1024 B

    hipLaunchKernelGGL(k_proto, dim3(256), dim3(256), 0, stream,
                       s_emb, s_tag, s_msk, protoB, p2part);
    hipLaunchKernelGGL(k_logits, dim3(256), dim3(256), 0, stream,
                       q_emb, q_msk, protoB, p2part, (float*)d_out);
}

// Round 3
// 168.223 us; speedup vs baseline: 1.2405x; 1.2405x over previous
//
#include <hip/hip_runtime.h>
#include <hip/hip_bf16.h>

typedef __bf16 bf16_t;
typedef __bf16 bf16x8 __attribute__((ext_vector_type(8)));
typedef __bf16 bf16x4 __attribute__((ext_vector_type(4)));
typedef float  f32x4  __attribute__((ext_vector_type(4)));

#define D_DIM 1024
#define N_LAB 64
#define ST_TOK 16384
#define QT_TOK 16384
#define TSPLIT 8
#define TSLICE (ST_TOK / TSPLIT)   // 2048 tokens per slice

// ---------------- Kernel 1: proto partial sums (scan + stream) -----------
// grid = 2048 blocks: blockIdx = (ts<<8) | (label<<2) | dq.
// Each block scans its 2048-token slice for (mask && tag==label), streams the
// matching rows' 256-dim quarter with coalesced f32x4 loads, and writes one
// fp32 partial-sum vector + count. 8 blocks/CU -> 32 waves/CU.
__global__ __launch_bounds__(256) void k_proto(
    const float* __restrict__ s_emb, const int* __restrict__ tag,
    const int* __restrict__ msk, float* __restrict__ part,
    int* __restrict__ cntPart)
{
    __shared__ int   list[TSLICE];
    __shared__ int   cnt;
    __shared__ float comb[4][256];

    const int tid   = threadIdx.x;
    const int lane  = tid & 63;
    const int wave  = tid >> 6;
    const int dq    = blockIdx.x & 3;
    const int label = (blockIdx.x >> 2) & 63;
    const int ts    = blockIdx.x >> 8;

    if (tid == 0) cnt = 0;
    __syncthreads();

    const int t0 = ts * TSLICE;
    for (int i = tid; i < TSLICE; i += 256) {
        const int t = t0 + i;
        if (msk[t] && tag[t] == label) list[atomicAdd(&cnt, 1)] = t;
    }
    __syncthreads();
    const int n = cnt;

    f32x4 acc = {0.f, 0.f, 0.f, 0.f};
    const float* base = s_emb + (size_t)dq * 256 + lane * 4;
    for (int i = wave; i < n; i += 4)
        acc += *(const f32x4*)(base + (size_t)list[i] * D_DIM);

    *(f32x4*)&comb[wave][lane * 4] = acc;
    __syncthreads();
    const float v = comb[0][tid] + comb[1][tid] + comb[2][tid] + comb[3][tid];
    part[((size_t)ts * N_LAB + label) * D_DIM + dq * 256 + tid] = v;
    if (dq == 0 && tid == 0) cntPart[ts * N_LAB + label] = n;
}

// ---------------- Kernel 2: finalize protos ------------------------------
// 64 blocks (one per label) x 256 threads; thread sums 8 partials for 4 dims,
// divides by count, writes bf16 proto + per-quarter p2 partials.
__global__ __launch_bounds__(256) void k_pfinal(
    const float* __restrict__ part, const int* __restrict__ cntPart,
    bf16_t* __restrict__ protoB, float* __restrict__ p2part)
{
    const int label = blockIdx.x;
    const int tid   = threadIdx.x;
    const int lane  = tid & 63;
    const int wave  = tid >> 6;

    int count = 0;
#pragma unroll
    for (int t = 0; t < TSPLIT; ++t) count += cntPart[t * N_LAB + label];
    const float inv = 1.f / fmaxf((float)count, 1.f);

    f32x4 s = {0.f, 0.f, 0.f, 0.f};
#pragma unroll
    for (int t = 0; t < TSPLIT; ++t)
        s += *(const f32x4*)(part + ((size_t)t * N_LAB + label) * D_DIM + tid * 4);
    s *= inv;

    bf16x4 b;
    b[0] = (bf16_t)s[0]; b[1] = (bf16_t)s[1];
    b[2] = (bf16_t)s[2]; b[3] = (bf16_t)s[3];
    *(bf16x4*)(protoB + (size_t)label * D_DIM + tid * 4) = b;

    float ss = s[0]*s[0] + s[1]*s[1] + s[2]*s[2] + s[3]*s[3];
    for (int off = 32; off; off >>= 1) ss += __shfl_down(ss, off);
    if (lane == 0) p2part[label * 4 + wave] = ss;   // wave w covers dims [w*256,(w+1)*256)
}

// ---------------- Kernel 3: logits via bf16 MFMA, K-split x4 -------------
// grid = 1024 blocks x 256 threads. Block covers 16 query rows x 64 labels;
// wave w handles K-quarter [w*256,(w+1)*256). LDS-reduce the 4 partial
// accumulators + q2 partials, then epilogue. 4 blocks/CU -> 16 waves/CU.
// A frag: A[m=lane&15][k=quad*8+j]; B frag: B[k][n=lane&15];
// C/D: col=lane&15, row=quad*4+reg.
__global__ __launch_bounds__(256) void k_logits(
    const float* __restrict__ q_emb, const int* __restrict__ q_mask,
    const bf16_t* __restrict__ protoB, const float* __restrict__ p2part,
    float* __restrict__ out)
{
    __shared__ float red[4][64][16];
    __shared__ float q2red[4][16];

    const int tid  = threadIdx.x;
    const int wave = tid >> 6;          // k-quarter
    const int lane = tid & 63;
    const int r15  = lane & 15;
    const int quad = lane >> 4;
    const int m_base = blockIdx.x * 16;
    const int k0 = wave * 256;

    const float*  aptr = q_emb  + (size_t)(m_base + r15) * D_DIM + k0 + quad * 8;
    const bf16_t* bptr = protoB + (size_t)r15 * D_DIM + k0 + quad * 8;

    f32x4 acc[4] = {};
    float q2p = 0.f;

#pragma unroll 4
    for (int kk = 0; kk < 256; kk += 32) {
        f32x4 a0 = *(const f32x4*)(aptr + kk);
        f32x4 a1 = *(const f32x4*)(aptr + kk + 4);
        bf16x8 af;
        af[0] = (bf16_t)a0[0]; af[1] = (bf16_t)a0[1];
        af[2] = (bf16_t)a0[2]; af[3] = (bf16_t)a0[3];
        af[4] = (bf16_t)a1[0]; af[5] = (bf16_t)a1[1];
        af[6] = (bf16_t)a1[2]; af[7] = (bf16_t)a1[3];
        q2p += a0[0]*a0[0] + a0[1]*a0[1] + a0[2]*a0[2] + a0[3]*a0[3]
             + a1[0]*a1[0] + a1[1]*a1[1] + a1[2]*a1[2] + a1[3]*a1[3];
#pragma unroll
        for (int t = 0; t < 4; ++t) {
            bf16x8 bfr = *(const bf16x8*)(bptr + (size_t)t * 16 * D_DIM + kk);
            acc[t] = __builtin_amdgcn_mfma_f32_16x16x32_bf16(af, bfr, acc[t], 0, 0, 0);
        }
    }

    // reduce q2 partial across the 4 quads (same r15)
    q2p += __shfl_xor(q2p, 16);
    q2p += __shfl_xor(q2p, 32);
    if (lane < 16) q2red[wave][lane] = q2p;

#pragma unroll
    for (int t = 0; t < 4; ++t) *(f32x4*)&red[wave][lane][t * 4] = acc[t];
    __syncthreads();

    // epilogue: thread = (l2 = tid&63, t = tid>>6); handles rows quad'*4+r, col t*16+c15
    const int l2  = tid & 63;
    const int c15 = l2 & 15;
    const int q2d = l2 >> 4;
    const int t   = tid >> 6;

    f32x4 sum = {};
#pragma unroll
    for (int w = 0; w < 4; ++w) sum += *(const f32x4*)&red[w][l2][t * 4];

    f32x4 pp = *(const f32x4*)(p2part + (size_t)(t * 16 + c15) * 4);
    const float p2v = pp[0] + pp[1] + pp[2] + pp[3];

#pragma unroll
    for (int r = 0; r < 4; ++r) {
        const int row = q2d * 4 + r;
        const float q2 = q2red[0][row] + q2red[1][row] + q2red[2][row] + q2red[3][row];
        const int gm = m_base + row;
        const float qm = (float)q_mask[gm];
        out[(size_t)gm * N_LAB + t * 16 + c15] = -(q2 + p2v - 2.f * sum[r]) * qm;
    }
}

extern "C" void kernel_launch(void* const* d_in, const int* in_sizes, int n_in,
                              void* d_out, int out_size, void* d_ws, size_t ws_size,
                              hipStream_t stream) {
    const float* s_emb = (const float*)d_in[0];
    const int*   s_tag = (const int*)d_in[1];
    const int*   s_msk = (const int*)d_in[2];
    const float* q_emb = (const float*)d_in[3];
    const int*   q_msk = (const int*)d_in[4];
    (void)in_sizes; (void)n_in; (void)out_size; (void)ws_size;

    char* ws = (char*)d_ws;
    float*  part    = (float*)ws;                      // 8*64*1024*4 = 2 MiB
    int*    cntPart = (int*)(ws + 2097152);            // 8*64*4 = 2 KiB
    bf16_t* protoB  = (bf16_t*)(ws + 2099200);         // 64*1024*2 = 128 KiB
    float*  p2part  = (float*)(ws + 2230272);          // 64*4*4 = 1 KiB

    hipLaunchKernelGGL(k_proto, dim3(2048), dim3(256), 0, stream,
                       s_emb, s_tag, s_msk, part, cntPart);
    hipLaunchKernelGGL(k_pfinal, dim3(64), dim3(256), 0, stream,
                       part, cntPart, protoB, p2part);
    hipLaunchKernelGGL(k_logits, dim3(1024), dim3(256), 0, stream,
                       q_emb, q_msk, protoB, p2part, (float*)d_out);
}

// Round 4
// 166.108 us; speedup vs baseline: 1.2562x; 1.0127x over previous
//
#include <hip/hip_runtime.h>
#include <hip/hip_bf16.h>

typedef __bf16 bf16_t;
typedef __bf16 bf16x8 __attribute__((ext_vector_type(8)));
typedef __bf16 bf16x4 __attribute__((ext_vector_type(4)));
typedef float  f32x4  __attribute__((ext_vector_type(4)));

#define D_DIM 1024
#define N_LAB 64
#define ST_TOK 16384
#define QT_TOK 16384
#define TSPLIT 32
#define TSLICE (ST_TOK / TSPLIT)   // 512 tokens per slice

// ---------------- Kernel 1: proto partial sums (scan + stream) -----------
// grid = 2048 blocks: blockIdx = (ts<<6) | label. Each block scans its
// 512-token slice once for (mask && tag==label); the 256 threads then
// cooperatively stream each matching FULL row (thread owns dims tid*4..+3),
// accumulating in registers. One fp32 partial row + count per block.
// 8 blocks/CU -> 32 waves/CU.
__global__ __launch_bounds__(256) void k_proto(
    const float* __restrict__ s_emb, const int* __restrict__ tag,
    const int* __restrict__ msk, float* __restrict__ part,
    int* __restrict__ cntPart)
{
    __shared__ int list[TSLICE];
    __shared__ int cnt;

    const int tid   = threadIdx.x;
    const int label = blockIdx.x & 63;
    const int ts    = blockIdx.x >> 6;

    if (tid == 0) cnt = 0;
    __syncthreads();

    const int t0 = ts * TSLICE;
    for (int i = tid; i < TSLICE; i += 256) {
        const int t = t0 + i;
        if (msk[t] && tag[t] == label) list[atomicAdd(&cnt, 1)] = t;
    }
    __syncthreads();
    const int n = cnt;

    f32x4 acc = {0.f, 0.f, 0.f, 0.f};
    const float* base = s_emb + tid * 4;
    int i = 0;
    for (; i + 2 <= n; i += 2) {
        f32x4 v0 = *(const f32x4*)(base + (size_t)list[i]     * D_DIM);
        f32x4 v1 = *(const f32x4*)(base + (size_t)list[i + 1] * D_DIM);
        acc += v0;
        acc += v1;
    }
    if (i < n) acc += *(const f32x4*)(base + (size_t)list[i] * D_DIM);

    *(f32x4*)(part + ((size_t)ts * N_LAB + label) * D_DIM + tid * 4) = acc;
    if (tid == 0) cntPart[ts * N_LAB + label] = n;
}

// ---------------- Kernel 2: finalize protos ------------------------------
// 64 blocks (one per label) x 256 threads; thread sums 32 partials for its
// 4 dims, divides by count, writes bf16 proto + per-quarter p2 partials.
__global__ __launch_bounds__(256) void k_pfinal(
    const float* __restrict__ part, const int* __restrict__ cntPart,
    bf16_t* __restrict__ protoB, float* __restrict__ p2part)
{
    const int label = blockIdx.x;
    const int tid   = threadIdx.x;
    const int lane  = tid & 63;
    const int wave  = tid >> 6;

    int count = 0;
#pragma unroll
    for (int t = 0; t < TSPLIT; ++t) count += cntPart[t * N_LAB + label];
    const float inv = 1.f / fmaxf((float)count, 1.f);

    f32x4 s = {0.f, 0.f, 0.f, 0.f};
#pragma unroll 8
    for (int t = 0; t < TSPLIT; ++t)
        s += *(const f32x4*)(part + ((size_t)t * N_LAB + label) * D_DIM + tid * 4);
    s *= inv;

    bf16x4 b;
    b[0] = (bf16_t)s[0]; b[1] = (bf16_t)s[1];
    b[2] = (bf16_t)s[2]; b[3] = (bf16_t)s[3];
    *(bf16x4*)(protoB + (size_t)label * D_DIM + tid * 4) = b;

    float ss = s[0]*s[0] + s[1]*s[1] + s[2]*s[2] + s[3]*s[3];
    for (int off = 32; off; off >>= 1) ss += __shfl_down(ss, off);
    if (lane == 0) p2part[label * 4 + wave] = ss;   // wave w covers dims [w*256,(w+1)*256)
}

// ---------------- Kernel 3: logits via bf16 MFMA, K-split x4 -------------
// grid = 1024 blocks x 256 threads. Block covers 16 query rows x 64 labels;
// wave w handles K-quarter [w*256,(w+1)*256). LDS-reduce the 4 partial
// accumulators + q2 partials, then epilogue. 4 blocks/CU -> 16 waves/CU.
// A frag: A[m=lane&15][k=quad*8+j]; B frag: B[k][n=lane&15];
// C/D: col=lane&15, row=quad*4+reg.
__global__ __launch_bounds__(256) void k_logits(
    const float* __restrict__ q_emb, const int* __restrict__ q_mask,
    const bf16_t* __restrict__ protoB, const float* __restrict__ p2part,
    float* __restrict__ out)
{
    __shared__ float red[4][64][16];
    __shared__ float q2red[4][16];

    const int tid  = threadIdx.x;
    const int wave = tid >> 6;          // k-quarter
    const int lane = tid & 63;
    const int r15  = lane & 15;
    const int quad = lane >> 4;
    const int m_base = blockIdx.x * 16;
    const int k0 = wave * 256;

    const float*  aptr = q_emb  + (size_t)(m_base + r15) * D_DIM + k0 + quad * 8;
    const bf16_t* bptr = protoB + (size_t)r15 * D_DIM + k0 + quad * 8;

    f32x4 acc[4] = {};
    float q2p = 0.f;

#pragma unroll 4
    for (int kk = 0; kk < 256; kk += 32) {
        f32x4 a0 = *(const f32x4*)(aptr + kk);
        f32x4 a1 = *(const f32x4*)(aptr + kk + 4);
        bf16x8 af;
        af[0] = (bf16_t)a0[0]; af[1] = (bf16_t)a0[1];
        af[2] = (bf16_t)a0[2]; af[3] = (bf16_t)a0[3];
        af[4] = (bf16_t)a1[0]; af[5] = (bf16_t)a1[1];
        af[6] = (bf16_t)a1[2]; af[7] = (bf16_t)a1[3];
        q2p += a0[0]*a0[0] + a0[1]*a0[1] + a0[2]*a0[2] + a0[3]*a0[3]
             + a1[0]*a1[0] + a1[1]*a1[1] + a1[2]*a1[2] + a1[3]*a1[3];
#pragma unroll
        for (int t = 0; t < 4; ++t) {
            bf16x8 bfr = *(const bf16x8*)(bptr + (size_t)t * 16 * D_DIM + kk);
            acc[t] = __builtin_amdgcn_mfma_f32_16x16x32_bf16(af, bfr, acc[t], 0, 0, 0);
        }
    }

    // reduce q2 partial across the 4 quads (same r15)
    q2p += __shfl_xor(q2p, 16);
    q2p += __shfl_xor(q2p, 32);
    if (lane < 16) q2red[wave][lane] = q2p;

#pragma unroll
    for (int t = 0; t < 4; ++t) *(f32x4*)&red[wave][lane][t * 4] = acc[t];
    __syncthreads();

    // epilogue: thread = (l2 = tid&63, t = tid>>6); handles rows q2d*4+r, col t*16+c15
    const int l2  = tid & 63;
    const int c15 = l2 & 15;
    const int q2d = l2 >> 4;
    const int t   = tid >> 6;

    f32x4 sum = {};
#pragma unroll
    for (int w = 0; w < 4; ++w) sum += *(const f32x4*)&red[w][l2][t * 4];

    f32x4 pp = *(const f32x4*)(p2part + (size_t)(t * 16 + c15) * 4);
    const float p2v = pp[0] + pp[1] + pp[2] + pp[3];

#pragma unroll
    for (int r = 0; r < 4; ++r) {
        const int row = q2d * 4 + r;
        const float q2 = q2red[0][row] + q2red[1][row] + q2red[2][row] + q2red[3][row];
        const int gm = m_base + row;
        const float qm = (float)q_mask[gm];
        out[(size_t)gm * N_LAB + t * 16 + c15] = -(q2 + p2v - 2.f * sum[r]) * qm;
    }
}

extern "C" void kernel_launch(void* const* d_in, const int* in_sizes, int n_in,
                              void* d_out, int out_size, void* d_ws, size_t ws_size,
                              hipStream_t stream) {
    const float* s_emb = (const float*)d_in[0];
    const int*   s_tag = (const int*)d_in[1];
    const int*   s_msk = (const int*)d_in[2];
    const float* q_emb = (const float*)d_in[3];
    const int*   q_msk = (const int*)d_in[4];
    (void)in_sizes; (void)n_in; (void)out_size; (void)ws_size;

    char* ws = (char*)d_ws;
    float*  part    = (float*)ws;                      // 32*64*1024*4 = 8 MiB
    int*    cntPart = (int*)(ws + 8388608);            // 32*64*4 = 8 KiB
    bf16_t* protoB  = (bf16_t*)(ws + 8396800);         // 64*1024*2 = 128 KiB
    float*  p2part  = (float*)(ws + 8527872);          // 64*4*4 = 1 KiB

    hipLaunchKernelGGL(k_proto, dim3(TSPLIT * N_LAB), dim3(256), 0, stream,
                       s_emb, s_tag, s_msk, part, cntPart);
    hipLaunchKernelGGL(k_pfinal, dim3(64), dim3(256), 0, stream,
                       part, cntPart, protoB, p2part);
    hipLaunchKernelGGL(k_logits, dim3(1024), dim3(256), 0, stream,
                       q_emb, q_msk, protoB, p2part, (float*)d_out);
}